// Round 8
// baseline (113.826 us; speedup 1.0000x reference)
//
#include <hip/hip_runtime.h>
#include <hip/hip_bf16.h>

#define BATCH    8192
#define NF       39      // num_fields
#define ED       64      // embed dim
#define RANK     32
#define NFRAG    15      // 5 l-slices x 3 k-chunks
#define KROWS    48      // k rows padded (frag k-index reaches 47)
#define KSTH     66      // EfT row stride in halves: 132 B = 33 dw -> +1 bank/row rotation

typedef _Float16 half2  __attribute__((ext_vector_type(2)));
typedef _Float16 half8  __attribute__((ext_vector_type(8)));
typedef float    f32x16 __attribute__((ext_vector_type(16)));

// ---- prep: 15 W A-fragments in per-lane MFMA layout (tiny, 4 blocks) ----
// wsW[(l*3+kc)*64 + lane] = half8 of W row j=lane&31, k = kc*16 + (lane>>5)*8 + e.
__global__ void prep_w(const float* __restrict__ W0,
                       const float* __restrict__ W1,
                       half8* __restrict__ wsW) {
    int d = blockIdx.x * 256 + threadIdx.x;
    if (d >= NFRAG * 64) return;
    int fid  = d >> 6;
    int lane = d & 63;
    int l = fid / 3, kc = fid % 3;
    int j = lane & 31, kh = lane >> 5;
    const float* base = (l < 2) ? (W0 + (l * RANK + j) * NF)
                                : (W1 + ((l - 2) * RANK + j) * NF);
    half8 h;
#pragma unroll
    for (int e = 0; e < 8; ++e) {
        int k = kc * 16 + kh * 8 + e;
        h[e] = (k < NF) ? (_Float16)base[k] : (_Float16)0.0f;
    }
    wsW[d] = h;
}

// ---- main: one wave = one sample; 10 dwordx4 gathers (4 rows/instr) ----
__global__ __launch_bounds__(256, 4) void tfm_kernel(
    const int*   __restrict__ x,        // (B, NF)
    const float* __restrict__ embed,    // (100000, ED) fp32
    const float* __restrict__ linw,     // (100000, 1)
    const float* __restrict__ lbias,    // (1,)
    const half8* __restrict__ wsW,      // [NFRAG][64]
    float*       __restrict__ out)      // (B,)
{
    __shared__ __align__(16) _Float16 Ws[NFRAG * 64 * 8];     // 15360 B
    __shared__ __align__(4)  _Float16 EfT[4][KROWS][KSTH];    // 25344 B, k-major, wave-private

    const int t    = threadIdx.x;
    const int lane = t & 63;
    const int w    = t >> 6;
    const int s    = blockIdx.x * 4 + w;     // one sample per wave

    const int sub = lane & 15;   // 16 lanes cover one 256B row (float4 each)
    const int g   = lane >> 4;   // 4 row-groups per instruction
    const int j   = lane & 31;
    const int kh  = lane >> 5;

    // ---- x vector + linear gather ----
    const int xi_v = (lane < NF) ? x[s * NF + lane] : 0;
    const float lv = (lane < NF) ? linw[xi_v] : 0.0f;

    // ---- stage W frags into LDS (independent; overlaps gathers) ----
    {
        const uint4* src = (const uint4*)wsW;
        uint4*       dst = (uint4*)Ws;
#pragma unroll
        for (int i = 0; i < NFRAG * 64 / 256; ++i)      // 3 full passes of 256
            dst[i * 256 + t] = src[i * 256 + t];
        if (t < NFRAG * 64 - 768) dst[768 + t] = src[768 + t];
    }

    // ---- gather: 10 x global_load_dwordx4, 4 rows per instruction ----
    // lane reads floats [sub*4 .. sub*4+3] of row (q*4+g); all 10 issued
    // before any conversion so they stay outstanding together.
    float4 gv[10];
#pragma unroll
    for (int q = 0; q < 10; ++q) {
        int kq = q * 4 + g;                       // 0..39 (39 = pad, xi=0 safe)
        int xi = __shfl(xi_v, kq, 64);
        gv[q] = *(const float4*)(embed + (size_t)xi * ED + sub * 4);
    }

    // ---- convert + scatter to k-major LDS: EfT[kq][i], i = sub*4.. ----
#pragma unroll
    for (int q = 0; q < 10; ++q) {
        int kq = q * 4 + g;
        half2 h01; h01[0] = (_Float16)gv[q].x; h01[1] = (_Float16)gv[q].y;
        half2 h23; h23[0] = (_Float16)gv[q].z; h23[1] = (_Float16)gv[q].w;
        *(half2*)&EfT[w][kq][sub * 4 + 0] = h01;
        *(half2*)&EfT[w][kq][sub * 4 + 2] = h23;
    }

    // ---- zero pad rows 39..47 (after gather writes; same-wave DS is in-order) ----
    if (lane < 33) {
        half2 z; z[0] = (_Float16)0.0f; z[1] = (_Float16)0.0f;
#pragma unroll
        for (int rr = 39; rr < KROWS; ++rr)
            *(half2*)&EfT[w][rr][lane * 2] = z;
    }

    const float bias = lbias[0];
    __syncthreads();   // Ws visible block-wide (EfT is wave-private)

    const half8* Wf = (const half8*)Ws;
    float ssum = lv;

#pragma unroll
    for (int tile = 0; tile < 2; ++tile) {
        const int c = tile * 32 + j;

        // B-frags from k-major LDS: 8 u16 reads per (kc); <=2 addrs/bank -> free
        half8 bf[3];
#pragma unroll
        for (int kc = 0; kc < 3; ++kc)
#pragma unroll
            for (int e = 0; e < 8; ++e)
                bf[kc][e] = EfT[w][kc * 16 + kh * 8 + e][c];

        // phase W0: 2 accumulators, folded immediately
        {
            f32x16 a0, a1;
#pragma unroll
            for (int e = 0; e < 16; ++e) { a0[e] = 0.0f; a1[e] = 0.0f; }
#pragma unroll
            for (int kc = 0; kc < 3; ++kc) {
                a0 = __builtin_amdgcn_mfma_f32_32x32x16_f16(Wf[(0 * 3 + kc) * 64 + lane], bf[kc], a0, 0, 0, 0);
                a1 = __builtin_amdgcn_mfma_f32_32x32x16_f16(Wf[(1 * 3 + kc) * 64 + lane], bf[kc], a1, 0, 0, 0);
            }
#pragma unroll
            for (int e = 0; e < 16; ++e) ssum += a0[e] * a1[e];
        }
        // phase W1: 3 accumulators (reuses W0's registers)
        {
            f32x16 c0, c1, c2;
#pragma unroll
            for (int e = 0; e < 16; ++e) { c0[e] = 0.0f; c1[e] = 0.0f; c2[e] = 0.0f; }
#pragma unroll
            for (int kc = 0; kc < 3; ++kc) {
                c0 = __builtin_amdgcn_mfma_f32_32x32x16_f16(Wf[(2 * 3 + kc) * 64 + lane], bf[kc], c0, 0, 0, 0);
                c1 = __builtin_amdgcn_mfma_f32_32x32x16_f16(Wf[(3 * 3 + kc) * 64 + lane], bf[kc], c1, 0, 0, 0);
                c2 = __builtin_amdgcn_mfma_f32_32x32x16_f16(Wf[(4 * 3 + kc) * 64 + lane], bf[kc], c2, 0, 0, 0);
            }
#pragma unroll
            for (int e = 0; e < 16; ++e) ssum += c0[e] * c1[e] * c2[e];
        }
    }

    // ---- 64-lane reduce, lane 0 writes ----
#pragma unroll
    for (int off = 32; off > 0; off >>= 1) ssum += __shfl_down(ssum, off, 64);
    if (lane == 0) out[s] = ssum + bias;
}

extern "C" void kernel_launch(void* const* d_in, const int* in_sizes, int n_in,
                              void* d_out, int out_size, void* d_ws, size_t ws_size,
                              hipStream_t stream) {
    const int*   x     = (const int*)  d_in[0];
    const float* embed = (const float*)d_in[1];
    const float* linw  = (const float*)d_in[2];
    const float* lbias = (const float*)d_in[3];
    const float* W0    = (const float*)d_in[4];
    const float* W1    = (const float*)d_in[5];
    float*       out   = (float*)d_out;
    half8*       wsW   = (half8*)d_ws;          // 15*64*16 B = 15360 B

    prep_w<<<(NFRAG * 64 + 255) / 256, 256, 0, stream>>>(W0, W1, wsW);
    // 2048 blocks x 4 waves x 1 sample = 8192
    tfm_kernel<<<BATCH / 4, 256, 0, stream>>>(x, embed, linw, lbias, wsW, out);
}